// Round 16
// baseline (230.128 us; speedup 1.0000x reference)
//
#include <hip/hip_runtime.h>
#include <cstdint>
#include <cstddef>

#define DEV __device__ __forceinline__

typedef __bf16 bf16x8 __attribute__((ext_vector_type(8)));
typedef __bf16 bf16x4 __attribute__((ext_vector_type(4)));
typedef short  short4v __attribute__((ext_vector_type(4)));
typedef float  f32x4  __attribute__((ext_vector_type(4)));

static constexpr int Bb  = 8;
static constexpr int S   = 1024;
static constexpr int DIM = 1024;
static constexpr int H   = 16;
static constexpr int DH  = 64;
static constexpr int HID = 512;
static constexpr int M   = Bb * S;   // 8192

DEV uint16_t f2bf(float f) {
  union { float f; uint32_t u; } v; v.f = f;
  uint32_t r = v.u + 0x7fffu + ((v.u >> 16) & 1u);
  return (uint16_t)(r >> 16);
}
DEV float bf2f(uint32_t u) {
  union { uint32_t u; float f; } v; v.u = u << 16;
  return v.f;
}

DEV void gl_lds16(const uint16_t* g, uint16_t* lds) {
  __builtin_amdgcn_global_load_lds(
      (const __attribute__((address_space(1))) void*)g,
      (__attribute__((address_space(3))) void*)lds, 16, 0, 0);
}

DEV bf16x8 ld8(const uint16_t* p) { return *reinterpret_cast<const bf16x8*>(p); }

// K=16 bf16 MFMA
#if __has_builtin(__builtin_amdgcn_mfma_f32_16x16x16bf16_1k)
DEV f32x4 mfma16(bf16x4 a, bf16x4 b, f32x4 c) {
  return __builtin_amdgcn_mfma_f32_16x16x16bf16_1k(
      __builtin_bit_cast(short4v, a), __builtin_bit_cast(short4v, b), c, 0, 0, 0);
}
#else
DEV f32x4 mfma16(bf16x4 a, bf16x4 b, f32x4 c) {
  asm volatile("v_mfma_f32_16x16x16_bf16 %0, %1, %2, %0" : "+v"(c) : "v"(a), "v"(b));
  return c;
}
#endif

// swizzled element offset for a [rows][64] bf16 LDS tile (row stride 128B).
DEV int swz(int row, int col) {
  return row * 64 + (((col >> 3) ^ (row & 7)) << 3) + (col & 7);
}

// ---------------- prep_all: x->bf16 convert + 6 weight transposes, ONE launch ----
__global__ __launch_bounds__(256) void prep_all(const float* __restrict__ x,
                                                uint16_t* __restrict__ x16,
                                                const float* __restrict__ Wq,
                                                const float* __restrict__ Wk,
                                                const float* __restrict__ Wv,
                                                const float* __restrict__ Wo,
                                                const float* __restrict__ W1,
                                                const float* __restrict__ W2,
                                                uint16_t* __restrict__ wqkv_t,
                                                uint16_t* __restrict__ wo_t,
                                                uint16_t* __restrict__ w1_t,
                                                uint16_t* __restrict__ w2_t) {
  int bid = blockIdx.x;
  int tid = threadIdx.x;
  if (bid < 4096) {
    int i = (bid * 256 + tid) * 8;
    const float4* p = reinterpret_cast<const float4*>(x + i);
    float4 a = p[0], b = p[1];
    uint4 pk;
    pk.x = (uint32_t)f2bf(a.x) | ((uint32_t)f2bf(a.y) << 16);
    pk.y = (uint32_t)f2bf(a.z) | ((uint32_t)f2bf(a.w) << 16);
    pk.z = (uint32_t)f2bf(b.x) | ((uint32_t)f2bf(b.y) << 16);
    pk.w = (uint32_t)f2bf(b.z) | ((uint32_t)f2bf(b.w) << 16);
    *reinterpret_cast<uint4*>(x16 + i) = pk;
    return;
  }
  bid -= 4096;
  const float* src;
  uint16_t* dst;
  int R, C, bx, by;
  if (bid < 4096) {
    int which = bid >> 10, id = bid & 1023;
    if (which == 0)      { src = Wq; dst = wqkv_t; }
    else if (which == 1) { src = Wk; dst = wqkv_t + 1048576; }
    else if (which == 2) { src = Wv; dst = wqkv_t + 2097152; }
    else                 { src = Wo; dst = wo_t; }
    R = 1024; C = 1024; bx = id & 31; by = id >> 5;
  } else if (bid < 4608) {
    int id = bid - 4096;
    src = W1; dst = w1_t; R = 1024; C = 512; bx = id & 15; by = id >> 4;
  } else {
    int id = bid - 4608;
    src = W2; dst = w2_t; R = 512; C = 1024; bx = id & 31; by = id >> 5;
  }
  __shared__ float tile[32][33];
  int c0 = bx * 32, r0 = by * 32;
  int tx = tid & 31, ty = tid >> 5;   // (32, 8)
  #pragma unroll
  for (int i = 0; i < 4; i++)
    tile[ty + i * 8][tx] = src[(size_t)(r0 + ty + i * 8) * C + c0 + tx];
  __syncthreads();
  #pragma unroll
  for (int i = 0; i < 4; i++)
    dst[(size_t)(c0 + ty + i * 8) * R + r0 + tx] = f2bf(tile[tx][ty + i * 8]);
}

// ---------------- GEMM 256x256 8-phase (HK-style schedule, plain HIP) ------------
// 8 waves (2M x 4N), BK=64, LDS 128KB = 2dbuf x 2half x 128x64 x {A,B}.
// Per K-tile: 4 phases = 4 C-quadrants x 16 MFMA. Stage slots per K-tile t:
// P1->A(t+1)h0, P2->A(t+1)h1, P3->B(t+2)h0, P4->B(t+2)h1; vmcnt(4) at P4
// confirms all of K-tile t+1 landed (only P3/P4 B-ops stay in flight).
__global__ __launch_bounds__(512, 2) void gemm8p(const uint16_t* __restrict__ A,
                                                 const uint16_t* __restrict__ Bt,
                                                 uint16_t* __restrict__ Cout,
                                                 uint16_t* __restrict__ vt,
                                                 int N, int K) {
  __shared__ __align__(16) uint16_t As[2][2][128 * 64];
  __shared__ __align__(16) uint16_t Bs[2][2][128 * 64];
  const int tid = threadIdx.x;
  const int w = tid >> 6, l = tid & 63;
  const int hi = l >> 4, c = l & 15;
  const int wr = w >> 2, wc = w & 3;    // 2 x 4 waves; per-wave 128x64 output
  int nwg = gridDim.x * gridDim.y;
  int lin = blockIdx.y * gridDim.x + blockIdx.x;
  if (!(nwg & 7)) lin = (lin & 7) * (nwg >> 3) + (lin >> 3);
  const int bx = lin % gridDim.x, by = lin / gridDim.x;
  const int m0 = by * 256, n0 = bx * 256;
  const uint16_t* Ag = A + (size_t)m0 * K;
  const uint16_t* Bg = Bt + (size_t)n0 * K;
  f32x4 acc[8][4] = {};

  // staging one half-tile (128 rows x 64 K): 2 gl_lds per thread, linear LDS
  // dest, swizzle folded into the global source column.
  const int srow = tid >> 3, sch = tid & 7;   // slot row/chunk for i=0
  auto stageA = [&](int kt, int d, int h) {
    #pragma unroll
    for (int i = 0; i < 2; i++) {
      int slot = i * 512 + tid;
      int row = slot >> 3, ch = slot & 7;
      int scol = (ch ^ (row & 7)) * 8;
      gl_lds16(Ag + (size_t)(h * 128 + row) * K + kt + scol, &As[d][h][slot * 8]);
    }
  };
  auto stageB = [&](int kt, int d, int h) {
    #pragma unroll
    for (int i = 0; i < 2; i++) {
      int slot = i * 512 + tid;
      int row = slot >> 3, ch = slot & 7;
      int scol = (ch ^ (row & 7)) * 8;
      gl_lds16(Bg + (size_t)(h * 128 + row) * K + kt + scol, &Bs[d][h][slot * 8]);
    }
  };

  // prologue: K-tile 0 fully (A,B), K-tile 1 B halves. vmcnt(4) leaves only
  // B1's 4 ops in flight -> K-tile 0 landed.
  stageA(0, 0, 0); stageA(0, 0, 1);
  stageB(0, 0, 0); stageB(0, 0, 1);
  stageB(64, 1, 0); stageB(64, 1, 1);
  asm volatile("s_waitcnt vmcnt(4)" ::: "memory");
  __builtin_amdgcn_s_barrier();

  const int NT = K >> 6;
  const int brow = (wc & 1) * 64;     // wave's row base inside its B half
  bf16x8 af[4][2], bfr[4][2];
  for (int t = 0; t < NT; t++) {
    const int d = t & 1;
    const uint16_t* Ah = As[d][wr];
    const uint16_t* Bh = Bs[d][wc >> 1];

    // ---- phase 1: read A mi0-3 + B ni0-1; stage A(t+1)h0; MFMA Q0 ----
    #pragma unroll
    for (int mi = 0; mi < 4; mi++)
      #pragma unroll
      for (int kk = 0; kk < 2; kk++)
        af[mi][kk] = ld8(&Ah[swz(mi * 16 + c, kk * 32 + hi * 8)]);
    #pragma unroll
    for (int ni = 0; ni < 2; ni++)
      #pragma unroll
      for (int kk = 0; kk < 2; kk++)
        bfr[ni][kk] = ld8(&Bh[swz(brow + ni * 16 + c, kk * 32 + hi * 8)]);
    if (t + 1 < NT) stageA((t + 1) << 6, d ^ 1, 0);
    __builtin_amdgcn_s_barrier();
    asm volatile("s_waitcnt lgkmcnt(0)" ::: "memory");
    __builtin_amdgcn_s_setprio(1);
    #pragma unroll
    for (int mi = 0; mi < 4; mi++)
      #pragma unroll
      for (int ni = 0; ni < 2; ni++) {
        acc[mi][ni] = __builtin_amdgcn_mfma_f32_16x16x32_bf16(af[mi][0], bfr[ni][0], acc[mi][ni], 0, 0, 0);
        acc[mi][ni] = __builtin_amdgcn_mfma_f32_16x16x32_bf16(af[mi][1], bfr[ni][1], acc[mi][ni], 0, 0, 0);
      }
    __builtin_amdgcn_s_setprio(0);
    __builtin_amdgcn_s_barrier();

    // ---- phase 2: read B ni2-3; stage A(t+1)h1; MFMA Q1 ----
    #pragma unroll
    for (int ni = 2; ni < 4; ni++)
      #pragma unroll
      for (int kk = 0; kk < 2; kk++)
        bfr[ni][kk] = ld8(&Bh[swz(brow + ni * 16 + c, kk * 32 + hi * 8)]);
    if (t + 1 < NT) stageA((t + 1) << 6, d ^ 1, 1);
    __builtin_amdgcn_s_barrier();
    asm volatile("s_waitcnt lgkmcnt(0)" ::: "memory");
    __builtin_amdgcn_s_setprio(1);
    #pragma unroll
    for (int mi = 0; mi < 4; mi++)
      #pragma unroll
      for (int ni = 2; ni < 4; ni++) {
        acc[mi][ni] = __builtin_amdgcn_mfma_f32_16x16x32_bf16(af[mi][0], bfr[ni][0], acc[mi][ni], 0, 0, 0);
        acc[mi][ni] = __builtin_amdgcn_mfma_f32_16x16x32_bf16(af[mi][1], bfr[ni][1], acc[mi][ni], 0, 0, 0);
      }
    __builtin_amdgcn_s_setprio(0);
    __builtin_amdgcn_s_barrier();

    // ---- phase 3: read A mi4-7; stage B(t+2)h0; MFMA Q2 ----
    #pragma unroll
    for (int mi = 0; mi < 4; mi++)
      #pragma unroll
      for (int kk = 0; kk < 2; kk++)
        af[mi][kk] = ld8(&Ah[swz((mi + 4) * 16 + c, kk * 32 + hi * 8)]);
    if (t + 2 < NT) stageB((t + 2) << 6, d, 0);
    __builtin_amdgcn_s_barrier();
    asm volatile("s_waitcnt lgkmcnt(0)" ::: "memory");
    __builtin_amdgcn_s_setprio(1);
    #pragma unroll
    for (int mi = 0; mi < 4; mi++)
      #pragma unroll
      for (int ni = 0; ni < 2; ni++) {
        acc[mi + 4][ni] = __builtin_amdgcn_mfma_f32_16x16x32_bf16(af[mi][0], bfr[ni][0], acc[mi + 4][ni], 0, 0, 0);
        acc[mi + 4][ni] = __builtin_amdgcn_mfma_f32_16x16x32_bf16(af[mi][1], bfr[ni][1], acc[mi + 4][ni], 0, 0, 0);
      }
    __builtin_amdgcn_s_setprio(0);
    __builtin_amdgcn_s_barrier();

    // ---- phase 4: stage B(t+2)h1; MFMA Q3; vmcnt checkpoint ----
    if (t + 2 < NT) stageB((t + 2) << 6, d, 1);
    __builtin_amdgcn_s_barrier();
    __builtin_amdgcn_s_setprio(1);
    #pragma unroll
    for (int mi = 0; mi < 4; mi++)
      #pragma unroll
      for (int ni = 2; ni < 4; ni++) {
        acc[mi + 4][ni] = __builtin_amdgcn_mfma_f32_16x16x32_bf16(af[mi][0], bfr[ni][0], acc[mi + 4][ni], 0, 0, 0);
        acc[mi + 4][ni] = __builtin_amdgcn_mfma_f32_16x16x32_bf16(af[mi][1], bfr[ni][1], acc[mi + 4][ni], 0, 0, 0);
      }
    __builtin_amdgcn_s_setprio(0);
    if (t + 1 < NT) {
      if (t + 2 < NT) {
        asm volatile("s_waitcnt vmcnt(4)" ::: "memory");   // K-tile t+1 landed
      } else {
        asm volatile("s_waitcnt vmcnt(0)" ::: "memory");   // tail: drain A(t+1)
      }
      __builtin_amdgcn_s_barrier();
    }
  }

  // epilogue: C-write (Q/K row-major; V fused-transposed)
  const int r0 = m0 + wr * 128 + hi * 4;
  const int c0 = n0 + wc * 64 + c;
  if (c0 >= 2048) {
    #pragma unroll
    for (int ni = 0; ni < 4; ni++) {
      int hd = c0 + ni * 16 - 2048;
      #pragma unroll
      for (int mi = 0; mi < 8; mi++) {
        int row = r0 + mi * 16;
        size_t vi = ((size_t)(row >> 10) * 1024 + hd) * 1024 + (row & 1023);
        uint2 pk;
        pk.x = (uint32_t)f2bf(acc[mi][ni][0]) | ((uint32_t)f2bf(acc[mi][ni][1]) << 16);
        pk.y = (uint32_t)f2bf(acc[mi][ni][2]) | ((uint32_t)f2bf(acc[mi][ni][3]) << 16);
        *(uint2*)&vt[vi] = pk;
      }
    }
  } else {
    #pragma unroll
    for (int mi = 0; mi < 8; mi++)
      #pragma unroll
      for (int ni = 0; ni < 4; ni++)
        #pragma unroll
        for (int r = 0; r < 4; r++)
          Cout[(size_t)(r0 + mi * 16 + r) * N + c0 + ni * 16] = f2bf(acc[mi][ni][r]);
  }
}

// ---------------- GEMM 128x128 pipelined (r11): depth-2, counted vmcnt -----------
template <int BIAS, int RELU>
__global__ __launch_bounds__(256) void gemm128p(const uint16_t* __restrict__ A,
                                                const uint16_t* __restrict__ Bt,
                                                const float* __restrict__ bias,
                                                uint16_t* __restrict__ Cout,
                                                int N, int K) {
  __shared__ __align__(16) uint16_t As[2][128 * 64];
  __shared__ __align__(16) uint16_t Bs[2][128 * 64];
  const int tid = threadIdx.x;
  const int w = tid >> 6, l = tid & 63;
  const int hi = l >> 4, c = l & 15;
  int nwg = gridDim.x * gridDim.y;
  int lin = blockIdx.y * gridDim.x + blockIdx.x;
  if (!(nwg & 7)) lin = (lin & 7) * (nwg >> 3) + (lin >> 3);
  const int bx = lin % gridDim.x, by = lin / gridDim.x;
  const int m0 = by * 128, n0 = bx * 128;
  const int wr = (w >> 1) * 64, wc = (w & 1) * 64;
  const uint16_t* Ag = A + (size_t)m0 * K;
  const uint16_t* Bg = Bt + (size_t)n0 * K;
  f32x4 acc[4][4] = {};

  const int srow = tid >> 3;
  const int scol = ((tid & 7) ^ (srow & 7)) * 8;
  auto stage = [&](int k0, int buf) {
    #pragma unroll
    for (int i = 0; i < 4; i++)
      gl_lds16(Ag + (size_t)(i * 32 + srow) * K + k0 + scol,
               &As[buf][(i * 256 + w * 64) * 8]);
    #pragma unroll
    for (int i = 0; i < 4; i++)
      gl_lds16(Bg + (size_t)(i * 32 + srow) * K + k0 + scol,
               &Bs[buf][(i * 256 + w * 64) * 8]);
  };

  stage(0, 0);
  stage(64, 1);
  asm volatile("s_waitcnt vmcnt(8)" ::: "memory");
  __builtin_amdgcn_s_barrier();

  const int NTK = K >> 6;
  for (int t = 0; t < NTK; t++) {
    const int cur = t & 1;
    const uint16_t* Ab = As[cur];
    const uint16_t* Bb = Bs[cur];
    bf16x8 af[4][2], bfr[4][2];
    #pragma unroll
    for (int i = 0; i < 4; i++)
      #pragma unroll
      for (int kk = 0; kk < 2; kk++) {
        af[i][kk]  = ld8(&Ab[swz(wr + i * 16 + c, kk * 32 + hi * 8)]);
        bfr[i][kk] = ld8(&Bb[swz(wc + i * 16 + c, kk * 32 + hi * 8)]);
      }
    #pragma unroll
    for (int i = 0; i < 4; i++)
      #pragma unroll
      for (int j = 0; j < 4; j++) {
        acc[i][j] = __builtin_amdgcn_mfma_f32_16x16x32_bf16(af[i][0], bfr[j][0], acc[i][j], 0, 0, 0);
        acc[i][j] = __builtin_amdgcn_mfma_f32_16x16x32_bf16(af[i][1], bfr[j][1], acc[i][j], 0, 0, 0);
      }
    if (t == NTK - 1) break;
    asm volatile("s_waitcnt lgkmcnt(0)" ::: "memory");
    __builtin_amdgcn_s_barrier();
    if (t + 2 < NTK) {
      stage((t + 2) << 6, cur);
      asm volatile("s_waitcnt vmcnt(8)" ::: "memory");
    } else {
      asm volatile("s_waitcnt vmcnt(0)" ::: "memory");
    }
    __builtin_amdgcn_s_barrier();
  }

  const int r0 = m0 + wr + hi * 4;
  const int c0 = n0 + wc + c;
  #pragma unroll
  for (int j = 0; j < 4; j++) {
    int col = c0 + j * 16;
    float bv = BIAS ? bias[col] : 0.0f;
    #pragma unroll
    for (int i = 0; i < 4; i++) {
      #pragma unroll
      for (int r = 0; r < 4; r++) {
        float v = acc[i][j][r] + bv;
        if (RELU) v = fmaxf(v, 0.0f);
        Cout[(size_t)(r0 + i * 16 + r) * N + col] = f2bf(v);
      }
    }
  }
}

// ---------------- flash attention v12 (r15 best): attn9 + prescale + setprio -----
__global__ __launch_bounds__(256, 4) void attn12(const uint16_t* __restrict__ qkv,
                                                 const uint16_t* __restrict__ vt,
                                                 uint16_t* __restrict__ ctx) {
  int blk = blockIdx.x;
  int xcd = blk & 7, idx = blk >> 3;
  int qt = idx & 7;
  int bh = xcd + 8 * (idx >> 3);
  int h = bh & 15, b = bh >> 4;
  int q0 = qt * 128;
  int tid = threadIdx.x;
  int w = tid >> 6, l = tid & 63;
  int hi = l >> 4, c = l & 15;

  __shared__ __align__(16) uint16_t Klds[2][64 * 64];
  __shared__ __align__(16) uint16_t Vlds[2][64 * 64];

  constexpr float C2 = 0.125f * 1.44269504f;
  const uint16_t* qbase = qkv + (size_t)(b * S + q0 + w * 32) * 3072 + h * 64;
  bf16x8 aq[2][2];
  #pragma unroll
  for (int qg = 0; qg < 2; qg++)
    #pragma unroll
    for (int dk = 0; dk < 2; dk++) {
      bf16x8 v = ld8(qbase + (size_t)(qg * 16 + c) * 3072 + dk * 32 + hi * 8);
      #pragma unroll
      for (int e = 0; e < 8; e++) v[e] = (__bf16)((float)v[e] * C2);
      aq[qg][dk] = v;
    }

  f32x4 acc[2][4] = {};
  float psum[2] = {};

  const uint16_t* kgbase = qkv + (size_t)(b * S) * 3072 + 1024 + h * 64;
  const uint16_t* vgbase = vt + (size_t)(b * 16 + h) * 64 * S;

  const int lr = l >> 3, lc = l & 7;
  const int scol = (lc ^ lr) * 8;
  auto stage = [&](int kt, int buf) {
    #pragma unroll
    for (int i = 0; i < 2; i++) {
      int slab = w * 2 + i;
      gl_lds16(kgbase + (size_t)(kt + slab * 8 + lr) * 3072 + scol,
               &Klds[buf][slab * 512]);
      gl_lds16(vgbase + (size_t)(slab * 8 + lr) * S + kt + scol,
               &Vlds[buf][slab * 512]);
    }
  };

  stage(0, 0);
  asm volatile("s_waitcnt vmcnt(0)" ::: "memory");
  __syncthreads();

  constexpr int NT = S / 64;
  for (int t = 0; t < NT; t++) {
    int cur = t & 1;
    if (t + 1 < NT) stage((t + 1) * 64, cur ^ 1);

    #pragma unroll
    for (int kb = 0; kb < 4; kb++) {
      bf16x8 kf0 = ld8(&Klds[cur][swz(kb * 16 + c, hi * 8)]);
      bf16x8 kf1 = ld8(&Klds[cur][swz(kb * 16 + c, 32 + hi * 8)]);
      bf16x4 pb[2];
      __builtin_amdgcn_s_setprio(1);
      f32x4 z0 = {0.f, 0.f, 0.f, 0.f}, z1 = {0.f, 0.f, 0.f, 0.f};
      z0 = __builtin_amdgcn_mfma_f32_16x16x32_bf16(kf0, aq[0][0], z0, 0, 0, 0);
      z0 = __builtin_amdgcn_mfma_f32_16x16x32_bf16(kf1, aq[0][1], z0, 0, 0, 0);
      z1 = __builtin_amdgcn_mfma_f32_16x16x32_bf16(kf0, aq[1][0], z1, 0, 0, 0);
      z1 = __builtin_amdgcn_mfma_f32_16x16x32_bf16(kf1, aq[1][1], z1, 0, 0, 0);
      __builtin_amdgcn_s_setprio(0);
      #pragma unroll
      for (int r = 0; r < 4; r++) {
        float p0 = exp2f(z0[r]);
        float p1 = exp2f(z1[r]);
        psum[0] += p0;
        psum[1] += p1;
        pb[0][r] = (__bf16)p0;
        pb[1][r] = (__bf16)p1;
      }
      __builtin_amdgcn_s_setprio(1);
      #pragma unroll
      for (int db = 0; db < 4; db++) {
        bf16x4 va = *(const bf16x4*)&Vlds[cur][swz(db * 16 + c, kb * 16 + hi * 4)];
        acc[0][db] = mfma16(va, pb[0], acc[0][db]);
        acc[1][db] = mfma16(va, pb[1], acc[1][db]);
      }
      __builtin_amdgcn_s_setprio(0);
    }

    if (t + 1 < NT) {
      asm volatile("s_waitcnt vmcnt(0)" ::: "memory");
      __syncthreads();
    }
  }

  #pragma unroll
  for (int qg = 0; qg < 2; qg++) {
    psum[qg] += __shfl_xor(psum[qg], 16);
    psum[qg] += __shfl_xor(psum[qg], 32);
  }

  __syncthreads();

  uint16_t* Bw = &Vlds[w >> 1][(w & 1) * 2048];
  #pragma unroll
  for (int qg = 0; qg < 2; qg++) {
    float inv = 1.0f / psum[qg];
    int q = qg * 16 + c;
    #pragma unroll
    for (int db = 0; db < 4; db++) {
      uint2 pk;
      pk.x = (uint32_t)f2bf(acc[qg][db][0] * inv) |
             ((uint32_t)f2bf(acc[qg][db][1] * inv) << 16);
      pk.y = (uint32_t)f2bf(acc[qg][db][2] * inv) |
             ((uint32_t)f2bf(acc[qg][db][3] * inv) << 16);
      int chunk4 = (db * 4 + hi) ^ (q & 15);
      *(uint2*)&Bw[q * 64 + chunk4 * 4] = pk;
    }
  }
  int rrow = l >> 3, rch = l & 7;
  size_t gq0 = (size_t)(b * S + q0 + w * 32);
  #pragma unroll
  for (int it = 0; it < 4; it++) {
    int row = it * 8 + rrow;
    int k0 = (2 * rch) ^ (row & 15);
    int base = (k0 & ~1) * 4;
    uint4 v = *(const uint4*)&Bw[row * 64 + base];
    if (row & 1) { uint32_t t0 = v.x, t1 = v.y; v.x = v.z; v.y = v.w; v.z = t0; v.w = t1; }
    *(uint4*)&ctx[(gq0 + row) * DIM + h * 64 + rch * 8] = v;
  }
}

// ---------------- LN1 per-wave-row ----------------
__global__ __launch_bounds__(256) void ln1_w(const uint16_t* __restrict__ a16,
                                             const uint16_t* __restrict__ x16,
                                             const float* __restrict__ g,
                                             const float* __restrict__ beta,
                                             uint16_t* __restrict__ h16) {
  int w = threadIdx.x >> 6, l = threadIdx.x & 63;
  size_t row = (size_t)blockIdx.x * 4 + w;
  const uint16_t* ap = a16 + row * DIM + l * 16;
  const uint16_t* xp = x16 + row * DIM + l * 16;
  uint4 av0 = *(const uint4*)ap, av1 = *(const uint4*)(ap + 8);
  uint4 xv0 = *(const uint4*)xp, xv1 = *(const uint4*)(xp + 8);
  float v[16];
  const uint32_t* au0 = (const uint32_t*)&av0;
  const uint32_t* au1 = (const uint32_t*)&av1;
  const uint32_t* xu0 = (const uint32_t*)&xv0;
  const uint32_t* xu1 = (const uint32_t*)&xv1;
  #pragma unroll
  for (int j = 0; j < 4; j++) {
    v[j * 2]     = bf2f(au0[j] & 0xffff) + bf2f(xu0[j] & 0xffff);
    v[j * 2 + 1] = bf2f(au0[j] >> 16)    + bf2f(xu0[j] >> 16);
    v[8 + j * 2]     = bf2f(au1[j] & 0xffff) + bf2f(xu1[j] & 0xffff);
    v[8 + j * 2 + 1] = bf2f(au1[j] >> 16)    + bf2f(xu1[j] >> 16);
  }
  float s = 0.f, sq = 0.f;
  #pragma unroll
  for (int j = 0; j < 16; j++) { s += v[j]; sq += v[j] * v[j]; }
  #pragma unroll
  for (int off = 32; off >= 1; off >>= 1) {
    s += __shfl_xor(s, off);
    sq += __shfl_xor(sq, off);
  }
  float mu = s * (1.0f / DIM);
  float var = sq * (1.0f / DIM) - mu * mu;
  float rstd = rsqrtf(var + 1e-5f);
  const float4* gp = (const float4*)(g + l * 16);
  const float4* bp = (const float4*)(beta + l * 16);
  uint4 o0, o1;
  uint32_t* ou0 = (uint32_t*)&o0;
  uint32_t* ou1 = (uint32_t*)&o1;
  #pragma unroll
  for (int q = 0; q < 2; q++) {
    float4 gv = gp[q], bv = bp[q];
    float e0 = (v[q * 4 + 0] - mu) * rstd * gv.x + bv.x;
    float e1 = (v[q * 4 + 1] - mu) * rstd * gv.y + bv.y;
    float e2 = (v[q * 4 + 2] - mu) * rstd * gv.z + bv.z;
    float e3 = (v[q * 4 + 3] - mu) * rstd * gv.w + bv.w;
    ou0[q * 2]     = (uint32_t)f2bf(e0) | ((uint32_t)f2bf(e1) << 16);
    ou0[q * 2 + 1] = (uint32_t)f2bf(e2) | ((uint32_t)f2bf(e3) << 16);
    float4 gv2 = gp[2 + q], bv2 = bp[2 + q];
    float f0 = (v[8 + q * 4 + 0] - mu) * rstd * gv2.x + bv2.x;
    float f1 = (v[8 + q * 4 + 1] - mu) * rstd * gv2.y + bv2.y;
    float f2 = (v[8 + q * 4 + 2] - mu) * rstd * gv2.z + bv2.z;
    float f3 = (v[8 + q * 4 + 3] - mu) * rstd * gv2.w + bv2.w;
    ou1[q * 2]     = (uint32_t)f2bf(f0) | ((uint32_t)f2bf(f1) << 16);
    ou1[q * 2 + 1] = (uint32_t)f2bf(f2) | ((uint32_t)f2bf(f3) << 16);
  }
  uint16_t* hp = h16 + row * DIM + l * 16;
  *(uint4*)hp = o0;
  *(uint4*)(hp + 8) = o1;
}

// ---------------- LN2 per-wave-row ----------------
__global__ __launch_bounds__(256) void ln2_w(const uint16_t* __restrict__ ff16,
                                             const uint16_t* __restrict__ h16,
                                             const float* __restrict__ g,
                                             const float* __restrict__ beta,
                                             float* __restrict__ out_f) {
  int w = threadIdx.x >> 6, l = threadIdx.x & 63;
  size_t row = (size_t)blockIdx.x * 4 + w;
  const uint16_t* ap = ff16 + row * DIM + l * 16;
  const uint16_t* xp = h16 + row * DIM + l * 16;
  uint4 av0 = *(const uint4*)ap, av1 = *(const uint4*)(ap + 8);
  uint4 xv0 = *(const uint4*)xp, xv1 = *(const uint4*)(xp + 8);
  float v[16];
  const uint32_t* au0 = (const uint32_t*)&av0;
  const uint32_t* au1 = (const uint32_t*)&av1;
  const uint32_t* xu0 = (const uint32_t*)&xv0;
  const uint32_t* xu1 = (const uint32_t*)&xv1;
  #pragma unroll
  for (int j = 0; j < 4; j++) {
    v[j * 2]     = bf2f(au0[j] & 0xffff) + bf2f(xu0[j] & 0xffff);
    v[j * 2 + 1] = bf2f(au0[j] >> 16)    + bf2f(xu0[j] >> 16);
    v[8 + j * 2]     = bf2f(au1[j] & 0xffff) + bf2f(xu1[j] & 0xffff);
    v[8 + j * 2 + 1] = bf2f(au1[j] >> 16)    + bf2f(xu1[j] >> 16);
  }
  float s = 0.f, sq = 0.f;
  #pragma unroll
  for (int j = 0; j < 16; j++) { s += v[j]; sq += v[j] * v[j]; }
  #pragma unroll
  for (int off = 32; off >= 1; off >>= 1) {
    s += __shfl_xor(s, off);
    sq += __shfl_xor(sq, off);
  }
  float mu = s * (1.0f / DIM);
  float var = sq * (1.0f / DIM) - mu * mu;
  float rstd = rsqrtf(var + 1e-5f);
  const float4* gp = (const float4*)(g + l * 16);
  const float4* bp = (const float4*)(beta + l * 16);
  float* op = out_f + row * DIM + l * 16;
  #pragma unroll
  for (int q = 0; q < 4; q++) {
    float4 gv = gp[q], bv = bp[q];
    float4 o;
    o.x = (v[q * 4 + 0] - mu) * rstd * gv.x + bv.x;
    o.y = (v[q * 4 + 1] - mu) * rstd * gv.y + bv.y;
    o.z = (v[q * 4 + 2] - mu) * rstd * gv.z + bv.z;
    o.w = (v[q * 4 + 3] - mu) * rstd * gv.w + bv.w;
    *(float4*)(op + q * 4) = o;
  }
}

extern "C" void kernel_launch(void* const* d_in, const int* in_sizes, int n_in,
                              void* d_out, int out_size, void* d_ws, size_t ws_size,
                              hipStream_t stream) {
  const float* x    = (const float*)d_in[0];
  const float* Wq   = (const float*)d_in[1];
  const float* Wk   = (const float*)d_in[2];
  const float* Wv   = (const float*)d_in[3];
  const float* Wo   = (const float*)d_in[4];
  const float* ln1g = (const float*)d_in[5];
  const float* ln1b = (const float*)d_in[6];
  const float* W1   = (const float*)d_in[7];
  const float* b1   = (const float*)d_in[8];
  const float* W2   = (const float*)d_in[9];
  const float* b2   = (const float*)d_in[10];
  const float* ln2g = (const float*)d_in[11];
  const float* ln2b = (const float*)d_in[12];
  float* out = (float*)d_out;

  char* ws = (char*)d_ws;
  uint16_t* wqkv_t = (uint16_t*)(ws + 0);                 // [3072][1024] bf16
  uint16_t* wo_t   = (uint16_t*)(ws + 6291456);           // [1024][1024]
  uint16_t* w1_t   = (uint16_t*)(ws + 8388608);           // [512][1024]
  uint16_t* w2_t   = (uint16_t*)(ws + 9437184);           // [1024][512]
  uint16_t* x16    = (uint16_t*)(ws + 10485760);          // [8192][1024] (stays live)
  uint16_t* qkv16  = (uint16_t*)(ws + 27262976);          // [8192][3072] (Q,K used)
  uint16_t* mha16  = (uint16_t*)(ws + 27262976);          // reuse (qkv dead after attn)
  uint16_t* ff16   = (uint16_t*)(ws + 27262976);          // reuse (after ln1)
  uint16_t* h16    = (uint16_t*)(ws + 60817408);          // [8192][1024]
  uint16_t* vt16   = (uint16_t*)(ws + 77594624);          // [128][64][1024]
  uint16_t* mid16  = vt16;                                // reuse (vt dead after attn)
  uint16_t* ctx16  = (uint16_t*)(ws + 94371840);          // [8192][1024]

  // 1. prep: x convert + all weight transposes (one launch)
  prep_all<<<9216, 256, 0, stream>>>(x, x16, Wq, Wk, Wv, Wo, W1, W2,
                                     wqkv_t, wo_t, w1_t, w2_t);
  // 2. QKV projection: 8-phase 256^2 schedule (V fused-transposed into vt16)
  gemm8p<<<dim3(12, 32), 512, 0, stream>>>(x16, wqkv_t, qkv16, vt16, 3072, DIM);
  // 3. attention
  attn12<<<1024, 256, 0, stream>>>(qkv16, vt16, ctx16);
  // 4. output projection -> bf16
  gemm128p<0, 0><<<dim3(8, 64), 256, 0, stream>>>(ctx16, wo_t, nullptr,
                                                  mha16, DIM, DIM);
  // 5. LN1 -> bf16 h
  ln1_w<<<2048, 256, 0, stream>>>(mha16, x16, ln1g, ln1b, h16);
  // 6. FFN1 (bias + relu)
  gemm128p<1, 1><<<dim3(4, 64), 256, 0, stream>>>(h16, w1_t, b1,
                                                  mid16, HID, DIM);
  // 7. FFN2 (bias) -> bf16
  gemm128p<1, 0><<<dim3(8, 64), 256, 0, stream>>>(mid16, w2_t, b2,
                                                  ff16, DIM, HID);
  // 8. LN2 -> out
  ln2_w<<<2048, 256, 0, stream>>>(ff16, h16, ln2g, ln2b, out);
}

// Round 17
// 221.257 us; speedup vs baseline: 1.0401x; 1.0401x over previous
//
#include <hip/hip_runtime.h>
#include <cstdint>
#include <cstddef>

#define DEV __device__ __forceinline__

typedef __bf16 bf16x8 __attribute__((ext_vector_type(8)));
typedef __bf16 bf16x4 __attribute__((ext_vector_type(4)));
typedef short  short4v __attribute__((ext_vector_type(4)));
typedef float  f32x4  __attribute__((ext_vector_type(4)));

static constexpr int Bb  = 8;
static constexpr int S   = 1024;
static constexpr int DIM = 1024;
static constexpr int H   = 16;
static constexpr int DH  = 64;
static constexpr int HID = 512;
static constexpr int M   = Bb * S;   // 8192

DEV uint16_t f2bf(float f) {
  union { float f; uint32_t u; } v; v.f = f;
  uint32_t r = v.u + 0x7fffu + ((v.u >> 16) & 1u);
  return (uint16_t)(r >> 16);
}
DEV float bf2f(uint32_t u) {
  union { uint32_t u; float f; } v; v.u = u << 16;
  return v.f;
}

DEV void gl_lds16(const uint16_t* g, uint16_t* lds) {
  __builtin_amdgcn_global_load_lds(
      (const __attribute__((address_space(1))) void*)g,
      (__attribute__((address_space(3))) void*)lds, 16, 0, 0);
}

DEV bf16x8 ld8(const uint16_t* p) { return *reinterpret_cast<const bf16x8*>(p); }

// K=16 bf16 MFMA
#if __has_builtin(__builtin_amdgcn_mfma_f32_16x16x16bf16_1k)
DEV f32x4 mfma16(bf16x4 a, bf16x4 b, f32x4 c) {
  return __builtin_amdgcn_mfma_f32_16x16x16bf16_1k(
      __builtin_bit_cast(short4v, a), __builtin_bit_cast(short4v, b), c, 0, 0, 0);
}
#else
DEV f32x4 mfma16(bf16x4 a, bf16x4 b, f32x4 c) {
  asm volatile("v_mfma_f32_16x16x16_bf16 %0, %1, %2, %0" : "+v"(c) : "v"(a), "v"(b));
  return c;
}
#endif

// swizzled element offset for a [rows][64] bf16 LDS tile (row stride 128B).
DEV int swz(int row, int col) {
  return row * 64 + (((col >> 3) ^ (row & 7)) << 3) + (col & 7);
}

// ---------------- prep_all: x->bf16 convert + 6 weight transposes, ONE launch ----
__global__ __launch_bounds__(256) void prep_all(const float* __restrict__ x,
                                                uint16_t* __restrict__ x16,
                                                const float* __restrict__ Wq,
                                                const float* __restrict__ Wk,
                                                const float* __restrict__ Wv,
                                                const float* __restrict__ Wo,
                                                const float* __restrict__ W1,
                                                const float* __restrict__ W2,
                                                uint16_t* __restrict__ wqkv_t,
                                                uint16_t* __restrict__ wo_t,
                                                uint16_t* __restrict__ w1_t,
                                                uint16_t* __restrict__ w2_t) {
  int bid = blockIdx.x;
  int tid = threadIdx.x;
  if (bid < 4096) {
    int i = (bid * 256 + tid) * 8;
    const float4* p = reinterpret_cast<const float4*>(x + i);
    float4 a = p[0], b = p[1];
    uint4 pk;
    pk.x = (uint32_t)f2bf(a.x) | ((uint32_t)f2bf(a.y) << 16);
    pk.y = (uint32_t)f2bf(a.z) | ((uint32_t)f2bf(a.w) << 16);
    pk.z = (uint32_t)f2bf(b.x) | ((uint32_t)f2bf(b.y) << 16);
    pk.w = (uint32_t)f2bf(b.z) | ((uint32_t)f2bf(b.w) << 16);
    *reinterpret_cast<uint4*>(x16 + i) = pk;
    return;
  }
  bid -= 4096;
  const float* src;
  uint16_t* dst;
  int R, C, bx, by;
  if (bid < 4096) {
    int which = bid >> 10, id = bid & 1023;
    if (which == 0)      { src = Wq; dst = wqkv_t; }
    else if (which == 1) { src = Wk; dst = wqkv_t + 1048576; }
    else if (which == 2) { src = Wv; dst = wqkv_t + 2097152; }
    else                 { src = Wo; dst = wo_t; }
    R = 1024; C = 1024; bx = id & 31; by = id >> 5;
  } else if (bid < 4608) {
    int id = bid - 4096;
    src = W1; dst = w1_t; R = 1024; C = 512; bx = id & 15; by = id >> 4;
  } else {
    int id = bid - 4608;
    src = W2; dst = w2_t; R = 512; C = 1024; bx = id & 31; by = id >> 5;
  }
  __shared__ float tile[32][33];
  int c0 = bx * 32, r0 = by * 32;
  int tx = tid & 31, ty = tid >> 5;   // (32, 8)
  #pragma unroll
  for (int i = 0; i < 4; i++)
    tile[ty + i * 8][tx] = src[(size_t)(r0 + ty + i * 8) * C + c0 + tx];
  __syncthreads();
  #pragma unroll
  for (int i = 0; i < 4; i++)
    dst[(size_t)(c0 + ty + i * 8) * R + r0 + tx] = f2bf(tile[tx][ty + i * 8]);
}

// ---------------- GEMM 128x128 pipelined: depth-2, counted vmcnt (proven) --------
template <int BIAS, int RELU, int FUSEV>
__global__ __launch_bounds__(256) void gemm128p(const uint16_t* __restrict__ A,
                                                const uint16_t* __restrict__ Bt,
                                                const float* __restrict__ bias,
                                                uint16_t* __restrict__ Cout,
                                                uint16_t* __restrict__ vt,
                                                int N, int K) {
  __shared__ __align__(16) uint16_t As[2][128 * 64];
  __shared__ __align__(16) uint16_t Bs[2][128 * 64];
  const int tid = threadIdx.x;
  const int w = tid >> 6, l = tid & 63;
  const int hi = l >> 4, c = l & 15;
  int nwg = gridDim.x * gridDim.y;
  int lin = blockIdx.y * gridDim.x + blockIdx.x;
  if (!(nwg & 7)) lin = (lin & 7) * (nwg >> 3) + (lin >> 3);
  const int bx = lin % gridDim.x, by = lin / gridDim.x;
  const int m0 = by * 128, n0 = bx * 128;
  const int wr = (w >> 1) * 64, wc = (w & 1) * 64;
  const uint16_t* Ag = A + (size_t)m0 * K;
  const uint16_t* Bg = Bt + (size_t)n0 * K;
  f32x4 acc[4][4] = {};

  const int srow = tid >> 3;
  const int scol = ((tid & 7) ^ (srow & 7)) * 8;
  auto stage = [&](int k0, int buf) {
    #pragma unroll
    for (int i = 0; i < 4; i++)
      gl_lds16(Ag + (size_t)(i * 32 + srow) * K + k0 + scol,
               &As[buf][(i * 256 + w * 64) * 8]);
    #pragma unroll
    for (int i = 0; i < 4; i++)
      gl_lds16(Bg + (size_t)(i * 32 + srow) * K + k0 + scol,
               &Bs[buf][(i * 256 + w * 64) * 8]);
  };

  stage(0, 0);
  stage(64, 1);
  asm volatile("s_waitcnt vmcnt(8)" ::: "memory");
  __builtin_amdgcn_s_barrier();

  const int NTK = K >> 6;
  for (int t = 0; t < NTK; t++) {
    const int cur = t & 1;
    const uint16_t* Ab = As[cur];
    const uint16_t* Bb = Bs[cur];
    bf16x8 af[4][2], bfr[4][2];
    #pragma unroll
    for (int i = 0; i < 4; i++)
      #pragma unroll
      for (int kk = 0; kk < 2; kk++) {
        af[i][kk]  = ld8(&Ab[swz(wr + i * 16 + c, kk * 32 + hi * 8)]);
        bfr[i][kk] = ld8(&Bb[swz(wc + i * 16 + c, kk * 32 + hi * 8)]);
      }
    #pragma unroll
    for (int i = 0; i < 4; i++)
      #pragma unroll
      for (int j = 0; j < 4; j++) {
        acc[i][j] = __builtin_amdgcn_mfma_f32_16x16x32_bf16(af[i][0], bfr[j][0], acc[i][j], 0, 0, 0);
        acc[i][j] = __builtin_amdgcn_mfma_f32_16x16x32_bf16(af[i][1], bfr[j][1], acc[i][j], 0, 0, 0);
      }
    if (t == NTK - 1) break;
    asm volatile("s_waitcnt lgkmcnt(0)" ::: "memory");   // my ds_reads retired
    __builtin_amdgcn_s_barrier();                        // buf[cur] free
    if (t + 2 < NTK) {
      stage((t + 2) << 6, cur);
      asm volatile("s_waitcnt vmcnt(8)" ::: "memory");   // tile t+1 landed
    } else {
      asm volatile("s_waitcnt vmcnt(0)" ::: "memory");
    }
    __builtin_amdgcn_s_barrier();                        // buf[t+1] ready
  }

  const int r0 = m0 + wr + hi * 4;
  const int c0 = n0 + wc + c;
  if (FUSEV && c0 >= 2048) {
    #pragma unroll
    for (int j = 0; j < 4; j++) {
      int hd = c0 + j * 16 - 2048;
      #pragma unroll
      for (int i = 0; i < 4; i++) {
        int row = r0 + i * 16;
        size_t vi = ((size_t)(row >> 10) * 1024 + hd) * 1024 + (row & 1023);
        uint2 pk;
        pk.x = (uint32_t)f2bf(acc[i][j][0]) | ((uint32_t)f2bf(acc[i][j][1]) << 16);
        pk.y = (uint32_t)f2bf(acc[i][j][2]) | ((uint32_t)f2bf(acc[i][j][3]) << 16);
        *(uint2*)&vt[vi] = pk;
      }
    }
  } else {
    #pragma unroll
    for (int j = 0; j < 4; j++) {
      int col = c0 + j * 16;
      float bv = BIAS ? bias[col] : 0.0f;
      #pragma unroll
      for (int i = 0; i < 4; i++) {
        #pragma unroll
        for (int r = 0; r < 4; r++) {
          float v = acc[i][j][r] + bv;
          if (RELU) v = fmaxf(v, 0.0f);
          Cout[(size_t)(r0 + i * 16 + r) * N + col] = f2bf(v);
        }
      }
    }
  }
}

// ---------------- flash attention v12: attn9 + Q-prescale + setprio --------------
__global__ __launch_bounds__(256, 4) void attn12(const uint16_t* __restrict__ qkv,
                                                 const uint16_t* __restrict__ vt,
                                                 uint16_t* __restrict__ ctx) {
  int blk = blockIdx.x;
  int xcd = blk & 7, idx = blk >> 3;
  int qt = idx & 7;
  int bh = xcd + 8 * (idx >> 3);
  int h = bh & 15, b = bh >> 4;
  int q0 = qt * 128;
  int tid = threadIdx.x;
  int w = tid >> 6, l = tid & 63;
  int hi = l >> 4, c = l & 15;

  __shared__ __align__(16) uint16_t Klds[2][64 * 64];
  __shared__ __align__(16) uint16_t Vlds[2][64 * 64];

  constexpr float C2 = 0.125f * 1.44269504f;
  const uint16_t* qbase = qkv + (size_t)(b * S + q0 + w * 32) * 3072 + h * 64;
  bf16x8 aq[2][2];
  #pragma unroll
  for (int qg = 0; qg < 2; qg++)
    #pragma unroll
    for (int dk = 0; dk < 2; dk++) {
      bf16x8 v = ld8(qbase + (size_t)(qg * 16 + c) * 3072 + dk * 32 + hi * 8);
      #pragma unroll
      for (int e = 0; e < 8; e++) v[e] = (__bf16)((float)v[e] * C2);
      aq[qg][dk] = v;
    }

  f32x4 acc[2][4] = {};
  float psum[2] = {};

  const uint16_t* kgbase = qkv + (size_t)(b * S) * 3072 + 1024 + h * 64;
  const uint16_t* vgbase = vt + (size_t)(b * 16 + h) * 64 * S;

  const int lr = l >> 3, lc = l & 7;
  const int scol = (lc ^ lr) * 8;
  auto stage = [&](int kt, int buf) {
    #pragma unroll
    for (int i = 0; i < 2; i++) {
      int slab = w * 2 + i;
      gl_lds16(kgbase + (size_t)(kt + slab * 8 + lr) * 3072 + scol,
               &Klds[buf][slab * 512]);
      gl_lds16(vgbase + (size_t)(slab * 8 + lr) * S + kt + scol,
               &Vlds[buf][slab * 512]);
    }
  };

  stage(0, 0);
  asm volatile("s_waitcnt vmcnt(0)" ::: "memory");
  __syncthreads();

  constexpr int NT = S / 64;
  for (int t = 0; t < NT; t++) {
    int cur = t & 1;
    if (t + 1 < NT) stage((t + 1) * 64, cur ^ 1);

    #pragma unroll
    for (int kb = 0; kb < 4; kb++) {
      bf16x8 kf0 = ld8(&Klds[cur][swz(kb * 16 + c, hi * 8)]);
      bf16x8 kf1 = ld8(&Klds[cur][swz(kb * 16 + c, 32 + hi * 8)]);
      bf16x4 pb[2];
      __builtin_amdgcn_s_setprio(1);
      f32x4 z0 = {0.f, 0.f, 0.f, 0.f}, z1 = {0.f, 0.f, 0.f, 0.f};
      z0 = __builtin_amdgcn_mfma_f32_16x16x32_bf16(kf0, aq[0][0], z0, 0, 0, 0);
      z0 = __builtin_amdgcn_mfma_f32_16x16x32_bf16(kf1, aq[0][1], z0, 0, 0, 0);
      z1 = __builtin_amdgcn_mfma_f32_16x16x32_bf16(kf0, aq[1][0], z1, 0, 0, 0);
      z1 = __builtin_amdgcn_mfma_f32_16x16x32_bf16(kf1, aq[1][1], z1, 0, 0, 0);
      __builtin_amdgcn_s_setprio(0);
      #pragma unroll
      for (int r = 0; r < 4; r++) {
        float p0 = exp2f(z0[r]);
        float p1 = exp2f(z1[r]);
        psum[0] += p0;
        psum[1] += p1;
        pb[0][r] = (__bf16)p0;
        pb[1][r] = (__bf16)p1;
      }
      __builtin_amdgcn_s_setprio(1);
      #pragma unroll
      for (int db = 0; db < 4; db++) {
        bf16x4 va = *(const bf16x4*)&Vlds[cur][swz(db * 16 + c, kb * 16 + hi * 4)];
        acc[0][db] = mfma16(va, pb[0], acc[0][db]);
        acc[1][db] = mfma16(va, pb[1], acc[1][db]);
      }
      __builtin_amdgcn_s_setprio(0);
    }

    if (t + 1 < NT) {
      asm volatile("s_waitcnt vmcnt(0)" ::: "memory");
      __syncthreads();
    }
  }

  #pragma unroll
  for (int qg = 0; qg < 2; qg++) {
    psum[qg] += __shfl_xor(psum[qg], 16);
    psum[qg] += __shfl_xor(psum[qg], 32);
  }

  __syncthreads();

  uint16_t* Bw = &Vlds[w >> 1][(w & 1) * 2048];
  #pragma unroll
  for (int qg = 0; qg < 2; qg++) {
    float inv = 1.0f / psum[qg];
    int q = qg * 16 + c;
    #pragma unroll
    for (int db = 0; db < 4; db++) {
      uint2 pk;
      pk.x = (uint32_t)f2bf(acc[qg][db][0] * inv) |
             ((uint32_t)f2bf(acc[qg][db][1] * inv) << 16);
      pk.y = (uint32_t)f2bf(acc[qg][db][2] * inv) |
             ((uint32_t)f2bf(acc[qg][db][3] * inv) << 16);
      int chunk4 = (db * 4 + hi) ^ (q & 15);
      *(uint2*)&Bw[q * 64 + chunk4 * 4] = pk;
    }
  }
  int rrow = l >> 3, rch = l & 7;
  size_t gq0 = (size_t)(b * S + q0 + w * 32);
  #pragma unroll
  for (int it = 0; it < 4; it++) {
    int row = it * 8 + rrow;
    int k0 = (2 * rch) ^ (row & 15);
    int base = (k0 & ~1) * 4;
    uint4 v = *(const uint4*)&Bw[row * 64 + base];
    if (row & 1) { uint32_t t0 = v.x, t1 = v.y; v.x = v.z; v.y = v.w; v.z = t0; v.w = t1; }
    *(uint4*)&ctx[(gq0 + row) * DIM + h * 64 + rch * 8] = v;
  }
}

// ---------------- LN1 per-wave-row: (bf16 a + bf16 x) -> bf16 h ------------------
__global__ __launch_bounds__(256) void ln1_w(const uint16_t* __restrict__ a16,
                                             const uint16_t* __restrict__ x16,
                                             const float* __restrict__ g,
                                             const float* __restrict__ beta,
                                             uint16_t* __restrict__ h16) {
  int w = threadIdx.x >> 6, l = threadIdx.x & 63;
  size_t row = (size_t)blockIdx.x * 4 + w;
  const uint16_t* ap = a16 + row * DIM + l * 16;
  const uint16_t* xp = x16 + row * DIM + l * 16;
  uint4 av0 = *(const uint4*)ap, av1 = *(const uint4*)(ap + 8);
  uint4 xv0 = *(const uint4*)xp, xv1 = *(const uint4*)(xp + 8);
  float v[16];
  const uint32_t* au0 = (const uint32_t*)&av0;
  const uint32_t* au1 = (const uint32_t*)&av1;
  const uint32_t* xu0 = (const uint32_t*)&xv0;
  const uint32_t* xu1 = (const uint32_t*)&xv1;
  #pragma unroll
  for (int j = 0; j < 4; j++) {
    v[j * 2]     = bf2f(au0[j] & 0xffff) + bf2f(xu0[j] & 0xffff);
    v[j * 2 + 1] = bf2f(au0[j] >> 16)    + bf2f(xu0[j] >> 16);
    v[8 + j * 2]     = bf2f(au1[j] & 0xffff) + bf2f(xu1[j] & 0xffff);
    v[8 + j * 2 + 1] = bf2f(au1[j] >> 16)    + bf2f(xu1[j] >> 16);
  }
  float s = 0.f, sq = 0.f;
  #pragma unroll
  for (int j = 0; j < 16; j++) { s += v[j]; sq += v[j] * v[j]; }
  #pragma unroll
  for (int off = 32; off >= 1; off >>= 1) {
    s += __shfl_xor(s, off);
    sq += __shfl_xor(sq, off);
  }
  float mu = s * (1.0f / DIM);
  float var = sq * (1.0f / DIM) - mu * mu;
  float rstd = rsqrtf(var + 1e-5f);
  const float4* gp = (const float4*)(g + l * 16);
  const float4* bp = (const float4*)(beta + l * 16);
  uint4 o0, o1;
  uint32_t* ou0 = (uint32_t*)&o0;
  uint32_t* ou1 = (uint32_t*)&o1;
  #pragma unroll
  for (int q = 0; q < 2; q++) {
    float4 gv = gp[q], bv = bp[q];
    float e0 = (v[q * 4 + 0] - mu) * rstd * gv.x + bv.x;
    float e1 = (v[q * 4 + 1] - mu) * rstd * gv.y + bv.y;
    float e2 = (v[q * 4 + 2] - mu) * rstd * gv.z + bv.z;
    float e3 = (v[q * 4 + 3] - mu) * rstd * gv.w + bv.w;
    ou0[q * 2]     = (uint32_t)f2bf(e0) | ((uint32_t)f2bf(e1) << 16);
    ou0[q * 2 + 1] = (uint32_t)f2bf(e2) | ((uint32_t)f2bf(e3) << 16);
    float4 gv2 = gp[2 + q], bv2 = bp[2 + q];
    float f0 = (v[8 + q * 4 + 0] - mu) * rstd * gv2.x + bv2.x;
    float f1 = (v[8 + q * 4 + 1] - mu) * rstd * gv2.y + bv2.y;
    float f2 = (v[8 + q * 4 + 2] - mu) * rstd * gv2.z + bv2.z;
    float f3 = (v[8 + q * 4 + 3] - mu) * rstd * gv2.w + bv2.w;
    ou1[q * 2]     = (uint32_t)f2bf(f0) | ((uint32_t)f2bf(f1) << 16);
    ou1[q * 2 + 1] = (uint32_t)f2bf(f2) | ((uint32_t)f2bf(f3) << 16);
  }
  uint16_t* hp = h16 + row * DIM + l * 16;
  *(uint4*)hp = o0;
  *(uint4*)(hp + 8) = o1;
}

// ---------------- LN2 per-wave-row: (bf16 ff + bf16 h) -> f32 out ----------------
__global__ __launch_bounds__(256) void ln2_w(const uint16_t* __restrict__ ff16,
                                             const uint16_t* __restrict__ h16,
                                             const float* __restrict__ g,
                                             const float* __restrict__ beta,
                                             float* __restrict__ out_f) {
  int w = threadIdx.x >> 6, l = threadIdx.x & 63;
  size_t row = (size_t)blockIdx.x * 4 + w;
  const uint16_t* ap = ff16 + row * DIM + l * 16;
  const uint16_t* xp = h16 + row * DIM + l * 16;
  uint4 av0 = *(const uint4*)ap, av1 = *(const uint4*)(ap + 8);
  uint4 xv0 = *(const uint4*)xp, xv1 = *(const uint4*)(xp + 8);
  float v[16];
  const uint32_t* au0 = (const uint32_t*)&av0;
  const uint32_t* au1 = (const uint32_t*)&av1;
  const uint32_t* xu0 = (const uint32_t*)&xv0;
  const uint32_t* xu1 = (const uint32_t*)&xv1;
  #pragma unroll
  for (int j = 0; j < 4; j++) {
    v[j * 2]     = bf2f(au0[j] & 0xffff) + bf2f(xu0[j] & 0xffff);
    v[j * 2 + 1] = bf2f(au0[j] >> 16)    + bf2f(xu0[j] >> 16);
    v[8 + j * 2]     = bf2f(au1[j] & 0xffff) + bf2f(xu1[j] & 0xffff);
    v[8 + j * 2 + 1] = bf2f(au1[j] >> 16)    + bf2f(xu1[j] >> 16);
  }
  float s = 0.f, sq = 0.f;
  #pragma unroll
  for (int j = 0; j < 16; j++) { s += v[j]; sq += v[j] * v[j]; }
  #pragma unroll
  for (int off = 32; off >= 1; off >>= 1) {
    s += __shfl_xor(s, off);
    sq += __shfl_xor(sq, off);
  }
  float mu = s * (1.0f / DIM);
  float var = sq * (1.0f / DIM) - mu * mu;
  float rstd = rsqrtf(var + 1e-5f);
  const float4* gp = (const float4*)(g + l * 16);
  const float4* bp = (const float4*)(beta + l * 16);
  float* op = out_f + row * DIM + l * 16;
  #pragma unroll
  for (int q = 0; q < 4; q++) {
    float4 gv = gp[q], bv = bp[q];
    float4 o;
    o.x = (v[q * 4 + 0] - mu) * rstd * gv.x + bv.x;
    o.y = (v[q * 4 + 1] - mu) * rstd * gv.y + bv.y;
    o.z = (v[q * 4 + 2] - mu) * rstd * gv.z + bv.z;
    o.w = (v[q * 4 + 3] - mu) * rstd * gv.w + bv.w;
    *(float4*)(op + q * 4) = o;
  }
}

extern "C" void kernel_launch(void* const* d_in, const int* in_sizes, int n_in,
                              void* d_out, int out_size, void* d_ws, size_t ws_size,
                              hipStream_t stream) {
  const float* x    = (const float*)d_in[0];
  const float* Wq   = (const float*)d_in[1];
  const float* Wk   = (const float*)d_in[2];
  const float* Wv   = (const float*)d_in[3];
  const float* Wo   = (const float*)d_in[4];
  const float* ln1g = (const float*)d_in[5];
  const float* ln1b = (const float*)d_in[6];
  const float* W1   = (const float*)d_in[7];
  const float* b1   = (const float*)d_in[8];
  const float* W2   = (const float*)d_in[9];
  const float* b2   = (const float*)d_in[10];
  const float* ln2g = (const float*)d_in[11];
  const float* ln2b = (const float*)d_in[12];
  float* out = (float*)d_out;

  char* ws = (char*)d_ws;
  uint16_t* wqkv_t = (uint16_t*)(ws + 0);                 // [3072][1024] bf16
  uint16_t* wo_t   = (uint16_t*)(ws + 6291456);           // [1024][1024]
  uint16_t* w1_t   = (uint16_t*)(ws + 8388608);           // [512][1024]
  uint16_t* w2_t   = (uint16_t*)(ws + 9437184);           // [1024][512]
  uint16_t* x16    = (uint16_t*)(ws + 10485760);          // [8192][1024] (stays live)
  uint16_t* qkv16  = (uint16_t*)(ws + 27262976);          // [8192][3072] (Q,K used)
  uint16_t* mha16  = (uint16_t*)(ws + 27262976);          // reuse (qkv dead after attn)
  uint16_t* ff16   = (uint16_t*)(ws + 27262976);          // reuse (after ln1)
  uint16_t* h16    = (uint16_t*)(ws + 60817408);          // [8192][1024]
  uint16_t* vt16   = (uint16_t*)(ws + 77594624);          // [128][64][1024]
  uint16_t* mid16  = vt16;                                // reuse (vt dead after attn)
  uint16_t* ctx16  = (uint16_t*)(ws + 94371840);          // [8192][1024]

  // 1. prep: x convert + all weight transposes (one launch)
  prep_all<<<9216, 256, 0, stream>>>(x, x16, Wq, Wk, Wv, Wo, W1, W2,
                                     wqkv_t, wo_t, w1_t, w2_t);
  // 2. QKV projection (V fused-transposed into vt16)
  gemm128p<0, 0, 1><<<dim3(24, 64), 256, 0, stream>>>(x16, wqkv_t, nullptr,
                                                      qkv16, vt16, 3072, DIM);
  // 3. attention
  attn12<<<1024, 256, 0, stream>>>(qkv16, vt16, ctx16);
  // 4. output projection -> bf16
  gemm128p<0, 0, 0><<<dim3(8, 64), 256, 0, stream>>>(ctx16, wo_t, nullptr,
                                                     mha16, nullptr, DIM, DIM);
  // 5. LN1 (residual + norm) -> bf16 h (per-wave rows)
  ln1_w<<<2048, 256, 0, stream>>>(mha16, x16, ln1g, ln1b, h16);
  // 6. FFN1 (bias + relu)
  gemm128p<1, 1, 0><<<dim3(4, 64), 256, 0, stream>>>(h16, w1_t, b1,
                                                     mid16, nullptr, HID, DIM);
  // 7. FFN2 (bias) -> bf16
  gemm128p<1, 0, 0><<<dim3(8, 64), 256, 0, stream>>>(mid16, w2_t, b2,
                                                     ff16, nullptr, DIM, HID);
  // 8. LN2 -> out (per-wave rows)
  ln2_w<<<2048, 256, 0, stream>>>(ff16, h16, ln2g, ln2b, out);
}